// Round 10
// baseline (312.293 us; speedup 1.0000x reference)
//
#include <hip/hip_runtime.h>
#include <math.h>

#define K_TOT 32
#define K_IND 16
#define K_MLP 16
#define DHID  64

// ws layout (ints): P floats [0..16), N floats [16..32), flag @32,
// rp = ((int*)ws)+64, length N+1.

// Prep: block 0 wave 0 computes collapsed-MLP constants
//   P_k = sum_{j: w1_j>0} w1_j*w2[j][k], N_k = sum_{j: w1_j<0} w1_j*w2[j][k]
// and flag = (all b1 == 0). All threads t<=N: rp[t] = lower_bound(recv, t).
__global__ void prep_kernel(const int* __restrict__ recv, int E, int N,
                            const float* __restrict__ w1,
                            const float* __restrict__ b1,
                            const float* __restrict__ w2,
                            float* __restrict__ wsP,
                            float* __restrict__ wsN,
                            int* __restrict__ wsflag,
                            int* __restrict__ rp) {
    if (blockIdx.x == 0 && threadIdx.x < 64) {
        int t = threadIdx.x;
        if (t < K_MLP) {
            float P = 0.f, Nn = 0.f;
            for (int j = 0; j < DHID; ++j) {
                float w = w1[j];
                float v = w2[j * K_MLP + t];
                P  += fmaxf(w, 0.f) * v;
                Nn += fminf(w, 0.f) * v;
            }
            wsP[t] = P; wsN[t] = Nn;
        }
        bool nz = (b1[t] != 0.f);
        unsigned long long mask = __ballot(nz);
        if (t == 0) *wsflag = (mask == 0ull) ? 1 : 0;
    }
    int tid = blockIdx.x * blockDim.x + threadIdx.x;
    if (tid <= N) {
        int lo = 0, hi = E;
        while (lo < hi) {
            int mid = (lo + hi) >> 1;
            if (recv[mid] < tid) lo = mid + 1; else hi = mid;
        }
        rp[tid] = lo;
    }
}

// FAST kernel only (all b1==0 && b==2). One wave = FOUR nodes:
// q = lane>>4 selects the node, cc = lane&15 the channel pair (indicator cc,
// mlp cc+16). One accumulator slot per channel -> no cross-slot merge.
// R9 taught: this layout cuts instrs/node 810->480 but VGPR=80 fell into the
// 4-waves/SIMD bucket (m69: waves halve at vgpr=64) -> occupancy 28%.
// Fix: generic path lives in a separate kernel; __launch_bounds__(256,8)
// pins this one under the 64-VGPR boundary for 8 waves/SIMD.
__global__ __launch_bounds__(256, 8) void graph4_fast_kernel(
        const float* __restrict__ nodes,
        const float* __restrict__ dist,
        const float* __restrict__ padv,
        const int*   __restrict__ send,
        const float* __restrict__ a_p,
        const float* __restrict__ b_p,
        const float* __restrict__ wg_self,
        const float* __restrict__ wg_gath,
        const float* __restrict__ bg,
        const float* __restrict__ wsP,
        const float* __restrict__ wsN,
        const int*   __restrict__ wsflag,
        const int*   __restrict__ rp,
        float* __restrict__ out,
        int N) {
    if (!((*wsflag != 0) && (fabsf(b_p[0]) == 2.0f))) return;

    int wave  = blockIdx.x * 4 + (threadIdx.x >> 6);
    int nbase = wave * 4;
    if (nbase >= N) return;
    int lane = threadIdx.x & 63;
    int q    = lane >> 4;     // node slot 0..3
    int cc   = lane & 15;     // channel pair index

    float a_c = fminf(fmaxf(a_p[0], 0.f), 1.f);
    float am  = 1.f - a_c;
    float Pk  = wsP[cc];
    float Nk  = wsN[cc];

    int n  = nbase + q;
    int nl = (n < N) ? n : N - 1;
    int e0 = rp[nl], e1 = rp[nl + 1];
    int len = (n < N) ? (e1 - e0) : 0;
    int eb  = (len > 0) ? e0 : 0;     // safe base for masked loads

    float nr0 = nodes[nl * K_TOT + cc];
    float nr1 = nodes[nl * K_TOT + cc + 16];
    float anr0 = a_c * nr0, anr1 = a_c * nr1;

    float lo = (float)cc * 0.0625f;
    float hi = lo + 0.0625f;

    float cnt = 0.f, si = 0.f;     // indicator (channel cc) of node q
    float l = 0.f, acc = 0.f;      // softmax  (channel cc+16) of node q

    // per-node max|d| (16-lane strided pre-pass + width-16 butterfly)
    float dm = 0.f;
    for (int i = cc; i < len; i += 16) dm = fmaxf(dm, fabsf(dist[eb + i]));
    dm = fmaxf(dm, __shfl_xor(dm, 1, 16));
    dm = fmaxf(dm, __shfl_xor(dm, 2, 16));
    dm = fmaxf(dm, __shfl_xor(dm, 4, 16));
    dm = fmaxf(dm, __shfl_xor(dm, 8, 16));
    float negM = -fmaxf(fabsf(Pk), fabsf(Nk)) * dm;

    // uniform trip count = max len over the 4 node slots
    int T = len;
    { int t2 = __shfl_xor(T, 16); T = T > t2 ? T : t2; }
    { int t2 = __shfl_xor(T, 32); T = T > t2 ? T : t2; }
    int last = (len > 0) ? (len - 1) : 0;

    for (int i = 0; i < T; ++i) {
        int  ii = i < last ? i : last;
        bool valid = i < len;
        int  idx = eb + ii;
        float d  = dist[idx];
        int   s  = send[idx];
        float pe = padv[idx];
        const float* nsr = nodes + (s * K_TOT + cc);
        float ns0 = nsr[0], ns1 = nsr[16];
        float t0 = fmaf(-am, ns0, anr0);
        float t1 = fmaf(-am, ns1, anr1);
        float pd0 = t0 * t0, pd1 = t1 * t1;
        bool inb = valid && (d > lo) && (d < hi);
        cnt += inb ? 1.f : 0.f;
        si   = inb ? fmaf(pe, pd0, si) : si;
        float qq = (d > 0.f) ? Pk : Nk;
        float p = __expf(fmaf(d, qq, negM));
        p = valid ? p : 0.f;
        l += p;
        acc = fmaf(p, pe * pd1, acc);
    }

    float g_ind = si / (cnt + 1e-5f);
    float g_mlp = (l > 0.f) ? (acc / l) : 0.f;

    // ---- fused epilogue: 2 passes, each handling 2 of the 4 nodes ----
    // pass p: half = lane>>5 selects node nbase+2p+half, oc = lane&31.
    // lane (half*32 + j) holds channel j of node (2p+half) in pre_g/pre_n.
    int half = lane >> 5;
    int oc   = lane & 31;
    int jb   = half << 5;
#pragma unroll
    for (int pass = 0; pass < 2; ++pass) {
        int tnode = nbase + 2 * pass + half;
        int src = (2 * pass + half) * 16 + (oc & 15);
        float sgi = __shfl(g_ind, src);
        float sgm = __shfl(g_mlp, src);
        float sn0 = __shfl(nr0, src);
        float sn1 = __shfl(nr1, src);
        float pre_g = (oc < 16) ? sgi : sgm;
        float pre_n = (oc < 16) ? sn0 : sn1;
        float o = 0.f;
#pragma unroll
        for (int j = 0; j < 32; ++j) {
            float gj = __shfl(pre_g, jb + j);
            float nj = __shfl(pre_n, jb + j);
            o = fmaf(nj, wg_self[j * K_TOT + oc], o);
            o = fmaf(gj, wg_gath[j * K_TOT + oc], o);
        }
        if (tnode < N) out[tnode * K_TOT + oc] = fmaxf(o + bg[oc], 0.f);
    }
}

// GENERIC kernel: wave per node, powf + full MLP + online softmax.
// Exits immediately when the fast kernel handles the input.
__global__ __launch_bounds__(256) void graph_generic_kernel(
        const float* __restrict__ nodes,
        const float* __restrict__ dist,
        const float* __restrict__ padv,
        const int*   __restrict__ send,
        const float* __restrict__ w1,
        const float* __restrict__ b1,
        const float* __restrict__ w2,
        const float* __restrict__ a_p,
        const float* __restrict__ b_p,
        const float* __restrict__ wg_self,
        const float* __restrict__ wg_gath,
        const float* __restrict__ bg,
        const int*   __restrict__ wsflag,
        const int*   __restrict__ rp,
        float* __restrict__ out,
        int N) {
    if ((*wsflag != 0) && (fabsf(b_p[0]) == 2.0f)) return;   // fast kernel owns it

    int wave = blockIdx.x * (blockDim.x >> 6) + (threadIdx.x >> 6);
    if (wave >= N) return;
    int n    = wave;
    int lane = threadIdx.x & 63;
    int eg   = lane >> 4;
    int cc   = lane & 15;

    float a_c = fminf(fmaxf(a_p[0], 0.f), 1.f);
    float am  = 1.f - a_c;
    float bc  = fabsf(b_p[0]);
    const float* nrow = nodes + n * K_TOT;
    float nr0 = nrow[cc];
    float nr1 = nrow[cc + 16];
    float anr0 = a_c * nr0, anr1 = a_c * nr1;
    int e0 = rp[n], eEnd = rp[n + 1];
    float lo = (float)cc * 0.0625f;
    float hi = lo + 0.0625f;
    float cnt = 0.f, si = 0.f, l = 0.f, acc = 0.f;
    float m_on = -INFINITY;

    for (int i = e0 + eg; i < eEnd; i += 4) {
        float d  = dist[i];
        int   s  = send[i];
        float pe = padv[i];
        const float* nsr = nodes + (s * K_TOT + cc);
        float ns0 = nsr[0], ns1 = nsr[16];
        float t0 = fabsf(fmaf(-am, ns0, anr0));
        float t1 = fabsf(fmaf(-am, ns1, anr1));
        float pd0 = powf(t0, bc), pd1 = powf(t1, bc);
        bool inb = (d > lo) && (d < hi);
        cnt += inb ? 1.f : 0.f;
        si  += inb ? pe * pd0 : 0.f;
        float mlp = 0.f;   // b2 cancels in the softmax ratio
        for (int j = 0; j < DHID; ++j) {
            float h = fmaxf(fmaf(d, w1[j], b1[j]), 0.f);
            mlp = fmaf(h, w2[j * K_MLP + cc], mlp);
        }
        float mn = fmaxf(m_on, mlp);
        float al = (m_on == -INFINITY) ? 0.f : __expf(m_on - mn);
        float pp = __expf(mlp - mn);
        l   = fmaf(l, al, pp);
        acc = fmaf(acc, al, pp * pe * pd1);
        m_on = mn;
    }
#pragma unroll
    for (int off = 16; off <= 32; off <<= 1) {
        cnt += __shfl_xor(cnt, off);
        si  += __shfl_xor(si,  off);
        float m2 = __shfl_xor(m_on, off), l2 = __shfl_xor(l, off), a2 = __shfl_xor(acc, off);
        float mn = fmaxf(m_on, m2);
        float f1 = (m_on == -INFINITY) ? 0.f : __expf(m_on - mn);
        float f2 = (m2   == -INFINITY) ? 0.f : __expf(m2 - mn);
        l   = l * f1 + l2 * f2;
        acc = acc * f1 + a2 * f2;
        m_on = mn;
    }
    float g_ind = si / (cnt + 1e-5f);
    float g_mlp = (l > 0.f) ? (acc / l) : 0.f;

    int h  = lane >> 5;
    int oc = lane & 31;
    float pre_g = ((lane >> 4) & 1) ? g_mlp : g_ind;
    float pre_n = ((lane >> 4) & 1) ? nr1 : nr0;
    float o_s = 0.f, o_g = 0.f;
    int jbase = h * 16;
#pragma unroll
    for (int jj = 0; jj < 16; ++jj) {
        int j = jbase + jj;
        float gj = __shfl(pre_g, j);
        float nj = __shfl(pre_n, j);
        o_s = fmaf(nj, wg_self[j * K_TOT + oc], o_s);
        o_g = fmaf(gj, wg_gath[j * K_TOT + oc], o_g);
    }
    float o = o_s + o_g;
    o += __shfl_xor(o, 32);
    if (h == 0) {
        out[n * K_TOT + oc] = fmaxf(o + bg[oc], 0.f);
    }
}

extern "C" void kernel_launch(void* const* d_in, const int* in_sizes, int n_in,
                              void* d_out, int out_size, void* d_ws, size_t ws_size,
                              hipStream_t stream) {
    const float* nodes   = (const float*)d_in[0];
    const float* dist    = (const float*)d_in[1];
    const float* padv    = (const float*)d_in[2];
    const int*   recv    = (const int*)d_in[3];
    const int*   send    = (const int*)d_in[4];
    const float* w1      = (const float*)d_in[5];
    const float* b1      = (const float*)d_in[6];
    const float* w2      = (const float*)d_in[7];
    const float* a_p     = (const float*)d_in[9];
    const float* b_p     = (const float*)d_in[10];
    const float* wg_self = (const float*)d_in[11];
    const float* wg_gath = (const float*)d_in[12];
    const float* bg      = (const float*)d_in[13];
    float* out = (float*)d_out;

    int N = in_sizes[0] / K_TOT;
    int E = in_sizes[1];

    float* wsf    = (float*)d_ws;
    float* wsP    = wsf;
    float* wsN    = wsf + 16;
    int*   wsflag = (int*)d_ws + 32;
    int*   rp     = (int*)d_ws + 64;

    prep_kernel<<<(N + 1 + 255) / 256, 256, 0, stream>>>(recv, E, N, w1, b1, w2,
                                                         wsP, wsN, wsflag, rp);
    int nwaves4 = (N + 3) / 4;
    graph4_fast_kernel<<<(nwaves4 + 3) / 4, 256, 0, stream>>>(
        nodes, dist, padv, send, a_p, b_p,
        wg_self, wg_gath, bg, wsP, wsN, wsflag, rp, out, N);
    graph_generic_kernel<<<(N + 3) / 4, 256, 0, stream>>>(
        nodes, dist, padv, send, w1, b1, w2, a_p, b_p,
        wg_self, wg_gath, bg, wsflag, rp, out, N);
}